// Round 2
// baseline (326.079 us; speedup 1.0000x reference)
//
#include <hip/hip_runtime.h>

// LeakyZOPlainOnce: 32-step LIF scan with LocalZO straight-through surrogate.
// inputs:  d_in[0] = x  (T*B*F fp32), d_in[1] = z (same shape)
// output:  d_out    = spikes (T*B*F fp32)
//
// Determinism note: spike = (h - surr*v) + surr*v is NOT exactly h when
// surr*v > 2 (residual ~1e-6 feeds the u recurrence). With 33.5M threshold
// decisions, some v land within 1e-7 of 0, so we must replicate the numpy
// fp32 op order EXACTLY: separate mul+add (no FMA contraction), true IEEE
// division by 0.1f, strict comparisons.
//
// R1: VEC 4 -> 2. Grid 1024 -> 2048 workgroups (8 wg/CU, 32 waves/CU vs the
// previous 16-wave ceiling that capped OccupancyPercent at ~38%). Explicit
// prefetch of step t+1's x/z before step t's dependent chain; nontemporal
// stores so the streamed-once output doesn't evict input lines from L2/L3.
// R2: native ext_vector_type(2) instead of HIP float2 — the nontemporal
// builtin only accepts clang vector types.

constexpr int BATCH = 128;
constexpr int FDIM  = 8192;
constexpr int STEP  = BATCH * FDIM;   // elements per time step = 1,048,576
constexpr int VEC   = 2;              // 2 floats per thread

typedef float v2f __attribute__((ext_vector_type(2)));

__global__ __launch_bounds__(256) void lif_zo_kernel(
    const float* __restrict__ x,
    const float* __restrict__ z,
    float* __restrict__ out,
    int T)
{
#pragma clang fp contract(off)
    const int tid = blockIdx.x * blockDim.x + threadIdx.x;
    long idx = (long)tid * VEC;

    float u[VEC];
#pragma unroll
    for (int c = 0; c < VEC; ++c) u[c] = 0.0f;

    // Preload step 0.
    v2f xt = *reinterpret_cast<const v2f*>(x + idx);
    v2f zt = *reinterpret_cast<const v2f*>(z + idx);

    for (int t = 0; t < T; ++t) {
        // Prefetch step t+1 (clamped on the last iteration; redundant L2-hit
        // reload, uniform select so no divergence) BEFORE the dependent chain.
        const long nidx = idx + STEP;
        const long pidx = (t + 1 < T) ? nidx : idx;
        const v2f xn = *reinterpret_cast<const v2f*>(x + pidx);
        const v2f zn = *reinterpret_cast<const v2f*>(z + pidx);

        v2f ss;
#pragma unroll
        for (int c = 0; c < VEC; ++c) {
            // u = beta*u + x   (separate mul + add, matches numpy)
            float uu = 0.5f * u[c];
            uu = uu + xt[c];
            // v = u - u_th
            float v = uu - 1.0f;
            // surr = (|z| / (2*delta)) * (|v| < delta*|z|)
            float az   = fabsf(zt[c]);
            float thr  = 0.05f * az;
            float ind  = (fabsf(v) < thr) ? 1.0f : 0.0f;
            float surr = (az / 0.1f) * ind;
            // h = (v > 0)
            float h = (v > 0.0f) ? 1.0f : 0.0f;
            // spike = (h - surr*v) + surr*v   (straight-through forward)
            float a     = surr * v;
            float spike = (h - a) + a;
            // u = u - spike * u_th
            u[c] = uu - spike * 1.0f;
            ss[c] = spike;
        }
        // Output is written once and never re-read: stream past L2/L3.
        __builtin_nontemporal_store(ss, reinterpret_cast<v2f*>(out + idx));

        xt = xn; zt = zn;
        idx = nidx;
    }
}

extern "C" void kernel_launch(void* const* d_in, const int* in_sizes, int n_in,
                              void* d_out, int out_size, void* d_ws, size_t ws_size,
                              hipStream_t stream)
{
    const float* x = (const float*)d_in[0];
    const float* z = (const float*)d_in[1];
    float* out = (float*)d_out;

    const int total = in_sizes[0];          // T * B * F
    const int T = total / STEP;             // = 32 for this problem

    const int nthreads = STEP / VEC;        // 524,288
    const int block = 256;
    const int grid = nthreads / block;      // 2048 -> 8 wg/CU

    lif_zo_kernel<<<grid, block, 0, stream>>>(x, z, out, T);
}

// Round 3
// 313.289 us; speedup vs baseline: 1.0408x; 1.0408x over previous
//
#include <hip/hip_runtime.h>

// LeakyZOPlainOnce: 32-step LIF scan with LocalZO straight-through surrogate.
// inputs:  d_in[0] = x  (T*B*F fp32), d_in[1] = z (same shape)
// output:  d_out    = spikes (T*B*F fp32)
//
// Determinism note: spike = (h - surr*v) + surr*v is NOT exactly h when
// surr*v > 2 (residual ~1e-6 feeds the u recurrence). We replicate the numpy
// fp32 op order EXACTLY: separate mul+add (no FMA contraction), true IEEE
// division by 0.1f, strict comparisons.
//
// R1/R2: VEC 4->2 raised occupancy 38%->71% but BW DROPPED (2.4->1.9 TB/s):
//   occupancy was not the constraint. Nontemporal store pinned the per-iter
//   vmcnt FIFO drain to HBM write latency (regression 113->139 us).
// R3: depth-4 software pipeline. Buffers statically indexed via 4x unroll
//   (runtime-indexed vector arrays spill to scratch). 8 loads in flight per
//   wave instead of 2; regular cached stores (complete at L2, and get 4
//   iterations of slack before any younger-load wait can force them).

constexpr int BATCH = 128;
constexpr int FDIM  = 8192;
constexpr int STEP  = BATCH * FDIM;   // elements per time step = 1,048,576
constexpr int VEC   = 2;              // 2 floats per thread
constexpr int PF    = 4;              // prefetch pipeline depth (T % PF == 0)

typedef float v2f __attribute__((ext_vector_type(2)));

__global__ __launch_bounds__(256, 8) void lif_zo_kernel(
    const float* __restrict__ x,
    const float* __restrict__ z,
    float* __restrict__ out,
    int T)
{
#pragma clang fp contract(off)
    const int tid = blockIdx.x * blockDim.x + threadIdx.x;
    const long base = (long)tid * VEC;

    float u0 = 0.0f, u1 = 0.0f;

    // Prologue: fill the pipeline with slabs 0..PF-1 (T=32 >= PF).
    v2f xb0 = *reinterpret_cast<const v2f*>(x + base + 0L * STEP);
    v2f zb0 = *reinterpret_cast<const v2f*>(z + base + 0L * STEP);
    v2f xb1 = *reinterpret_cast<const v2f*>(x + base + 1L * STEP);
    v2f zb1 = *reinterpret_cast<const v2f*>(z + base + 1L * STEP);
    v2f xb2 = *reinterpret_cast<const v2f*>(x + base + 2L * STEP);
    v2f zb2 = *reinterpret_cast<const v2f*>(z + base + 2L * STEP);
    v2f xb3 = *reinterpret_cast<const v2f*>(x + base + 3L * STEP);
    v2f zb3 = *reinterpret_cast<const v2f*>(z + base + 3L * STEP);

    // One LIF step on element pair (xt,zt); updates u0/u1, returns spikes.
    auto lif = [&](const v2f xt, const v2f zt) -> v2f {
        v2f ss;
        float uu, v, az, thr, ind, surr, h, a, spike;
        // lane-element 0
        uu = 0.5f * u0; uu = uu + xt[0];
        v  = uu - 1.0f;
        az = fabsf(zt[0]); thr = 0.05f * az;
        ind = (fabsf(v) < thr) ? 1.0f : 0.0f;
        surr = (az / 0.1f) * ind;
        h = (v > 0.0f) ? 1.0f : 0.0f;
        a = surr * v; spike = (h - a) + a;
        u0 = uu - spike * 1.0f; ss[0] = spike;
        // lane-element 1
        uu = 0.5f * u1; uu = uu + xt[1];
        v  = uu - 1.0f;
        az = fabsf(zt[1]); thr = 0.05f * az;
        ind = (fabsf(v) < thr) ? 1.0f : 0.0f;
        surr = (az / 0.1f) * ind;
        h = (v > 0.0f) ? 1.0f : 0.0f;
        a = surr * v; spike = (h - a) + a;
        u1 = uu - spike * 1.0f; ss[1] = spike;
        return ss;
    };

    // Main loop: 4x unrolled so pipeline buffers have static indices.
    for (int t = 0; t < T; t += PF) {
        {   // j = 0 : consume slab t, prefetch slab t+PF
            const long pt  = (t + 0 + PF < T) ? (long)(t + 0 + PF) : (long)(T - 1);
            const v2f xn = *reinterpret_cast<const v2f*>(x + base + pt * STEP);
            const v2f zn = *reinterpret_cast<const v2f*>(z + base + pt * STEP);
            v2f ss = lif(xb0, zb0);
            *reinterpret_cast<v2f*>(out + base + (long)(t + 0) * STEP) = ss;
            xb0 = xn; zb0 = zn;
        }
        {   // j = 1
            const long pt  = (t + 1 + PF < T) ? (long)(t + 1 + PF) : (long)(T - 1);
            const v2f xn = *reinterpret_cast<const v2f*>(x + base + pt * STEP);
            const v2f zn = *reinterpret_cast<const v2f*>(z + base + pt * STEP);
            v2f ss = lif(xb1, zb1);
            *reinterpret_cast<v2f*>(out + base + (long)(t + 1) * STEP) = ss;
            xb1 = xn; zb1 = zn;
        }
        {   // j = 2
            const long pt  = (t + 2 + PF < T) ? (long)(t + 2 + PF) : (long)(T - 1);
            const v2f xn = *reinterpret_cast<const v2f*>(x + base + pt * STEP);
            const v2f zn = *reinterpret_cast<const v2f*>(z + base + pt * STEP);
            v2f ss = lif(xb2, zb2);
            *reinterpret_cast<v2f*>(out + base + (long)(t + 2) * STEP) = ss;
            xb2 = xn; zb2 = zn;
        }
        {   // j = 3
            const long pt  = (t + 3 + PF < T) ? (long)(t + 3 + PF) : (long)(T - 1);
            const v2f xn = *reinterpret_cast<const v2f*>(x + base + pt * STEP);
            const v2f zn = *reinterpret_cast<const v2f*>(z + base + pt * STEP);
            v2f ss = lif(xb3, zb3);
            *reinterpret_cast<v2f*>(out + base + (long)(t + 3) * STEP) = ss;
            xb3 = xn; zb3 = zn;
        }
    }
}

extern "C" void kernel_launch(void* const* d_in, const int* in_sizes, int n_in,
                              void* d_out, int out_size, void* d_ws, size_t ws_size,
                              hipStream_t stream)
{
    const float* x = (const float*)d_in[0];
    const float* z = (const float*)d_in[1];
    float* out = (float*)d_out;

    const int total = in_sizes[0];          // T * B * F
    const int T = total / STEP;             // = 32 for this problem

    const int nthreads = STEP / VEC;        // 524,288
    const int block = 256;
    const int grid = nthreads / block;      // 2048 -> 8 wg/CU

    lif_zo_kernel<<<grid, block, 0, stream>>>(x, z, out, T);
}

// Round 4
// 313.065 us; speedup vs baseline: 1.0416x; 1.0007x over previous
//
#include <hip/hip_runtime.h>

// LeakyZOPlainOnce: 32-step LIF scan with LocalZO straight-through surrogate.
// inputs:  d_in[0] = x  (T*B*F fp32), d_in[1] = z (same shape)
// output:  d_out    = spikes (T*B*F fp32)
//
// Determinism note: spike = (h - surr*v) + surr*v is NOT exactly h when
// surr*v > 2 (residual ~1e-6 feeds the u recurrence). We replicate the numpy
// fp32 op order EXACTLY: separate mul+add (no FMA contraction), true IEEE
// division by 0.1f, strict comparisons.
//
// R1/R2: occupancy 38%->71% did NOT raise BW -> occupancy not the constraint.
// R3: depth-4 pipeline with rotation copies (xb0=xn) -> BW stuck at 2.5 TB/s.
//   Diagnosis: loop-carried register moves of loaded values force a
//   vmcnt-drain inside each sub-iteration -> effective prefetch depth ~1,
//   ~1 load in flight per wave (2.5 TB/s == ~190 B/wave in flight at ~900cy).
// R4: FULL UNROLL of T=32 (template). No back-edge -> no rotation moves ->
//   loads live in SSA until true consumption PF iterations later. PF=8,
//   VEC=4 (float4 1KB/wave-instr), no tail clamp-reload.

constexpr int BATCH = 128;
constexpr int FDIM  = 8192;
constexpr int STEP  = BATCH * FDIM;   // elements per time step = 1,048,576
constexpr int VEC   = 4;              // float4 per thread
constexpr int PF    = 8;              // prefetch pipeline depth

typedef float v4f __attribute__((ext_vector_type(4)));

__device__ __forceinline__ void lif_step(const v4f xt, const v4f zt,
                                         v4f& u, v4f& ss)
{
#pragma clang fp contract(off)
#pragma unroll
    for (int c = 0; c < VEC; ++c) {
        // u = beta*u + x   (separate mul + add, matches numpy)
        float uu = 0.5f * u[c];
        uu = uu + xt[c];
        // v = u - u_th
        float v = uu - 1.0f;
        // surr = (|z| / (2*delta)) * (|v| < delta*|z|)
        float az   = fabsf(zt[c]);
        float thr  = 0.05f * az;
        float ind  = (fabsf(v) < thr) ? 1.0f : 0.0f;
        float surr = (az / 0.1f) * ind;
        // h = (v > 0)
        float h = (v > 0.0f) ? 1.0f : 0.0f;
        // spike = (h - surr*v) + surr*v   (straight-through forward)
        float a     = surr * v;
        float spike = (h - a) + a;
        // u = u - spike * u_th
        u[c]  = uu - spike * 1.0f;
        ss[c] = spike;
    }
}

template<int T>
__global__ __launch_bounds__(256, 4) void lif_zo_unrolled(
    const float* __restrict__ x,
    const float* __restrict__ z,
    float* __restrict__ out)
{
#pragma clang fp contract(off)
    const int tid = blockIdx.x * blockDim.x + threadIdx.x;
    const long base = (long)tid * VEC;

    v4f u = {0.0f, 0.0f, 0.0f, 0.0f};

    // Pipeline buffers: statically indexed (t % PF is a constant after full
    // unroll), so these live entirely in registers with SSA renaming.
    v4f xb[PF], zb[PF];
#pragma unroll
    for (int j = 0; j < PF; ++j) {
        xb[j] = *reinterpret_cast<const v4f*>(x + base + (long)j * STEP);
        zb[j] = *reinterpret_cast<const v4f*>(z + base + (long)j * STEP);
    }

#pragma unroll
    for (int t = 0; t < T; ++t) {
        const int c = t % PF;
        const v4f xt = xb[c];
        const v4f zt = zb[c];
        // Prefetch slab t+PF into the slot just freed (compile-time guard:
        // no tail clamp-reload, no extra FETCH traffic).
        if (t + PF < T) {
            xb[c] = *reinterpret_cast<const v4f*>(x + base + (long)(t + PF) * STEP);
            zb[c] = *reinterpret_cast<const v4f*>(z + base + (long)(t + PF) * STEP);
        }
        v4f ss;
        lif_step(xt, zt, u, ss);
        *reinterpret_cast<v4f*>(out + base + (long)t * STEP) = ss;
    }
}

// Generic fallback for unexpected T (correctness only; T=32 in this problem).
__global__ __launch_bounds__(256, 4) void lif_zo_generic(
    const float* __restrict__ x,
    const float* __restrict__ z,
    float* __restrict__ out,
    int T)
{
#pragma clang fp contract(off)
    const int tid = blockIdx.x * blockDim.x + threadIdx.x;
    long idx = (long)tid * VEC;
    v4f u = {0.0f, 0.0f, 0.0f, 0.0f};
    for (int t = 0; t < T; ++t, idx += STEP) {
        const v4f xt = *reinterpret_cast<const v4f*>(x + idx);
        const v4f zt = *reinterpret_cast<const v4f*>(z + idx);
        v4f ss;
        lif_step(xt, zt, u, ss);
        *reinterpret_cast<v4f*>(out + idx) = ss;
    }
}

extern "C" void kernel_launch(void* const* d_in, const int* in_sizes, int n_in,
                              void* d_out, int out_size, void* d_ws, size_t ws_size,
                              hipStream_t stream)
{
    const float* x = (const float*)d_in[0];
    const float* z = (const float*)d_in[1];
    float* out = (float*)d_out;

    const int total = in_sizes[0];          // T * B * F
    const int T = total / STEP;             // = 32 for this problem

    const int nthreads = STEP / VEC;        // 262,144
    const int block = 256;
    const int grid = nthreads / block;      // 1024

    if (T == 32) {
        lif_zo_unrolled<32><<<grid, block, 0, stream>>>(x, z, out);
    } else {
        lif_zo_generic<<<grid, block, 0, stream>>>(x, z, out, T);
    }
}

// Round 6
// 310.422 us; speedup vs baseline: 1.0504x; 1.0085x over previous
//
#include <hip/hip_runtime.h>

// LeakyZOPlainOnce: 32-step LIF scan with LocalZO straight-through surrogate.
// inputs:  d_in[0] = x  (T*B*F fp32), d_in[1] = z (same shape)
// output:  d_out    = spikes (T*B*F fp32)
//
// Determinism: replicate numpy fp32 op order EXACTLY — separate mul+add (no
// FMA contraction), true IEEE division by 0.1f, strict comparisons.
//
// History:
//  R1/R2: occupancy 38%->71% did NOT raise BW -> occupancy not the constraint.
//  R3:    reg pipeline w/ rotation copies -> vmcnt drain per step, ~2.5 TB/s.
//  R4:    full unroll, compiler-scheduled: VGPR_Count=40 proves loads sunk to
//         point-of-use; effective prefetch depth ~1. 122 us.
//  R5:    inline-asm register pipeline: WRONG RESULTS — compiler may copy an
//         in-flight "=v" load dest before the hand-placed waitcnt (the value
//         doesn't exist yet). Register-resident async loads are unfixable at
//         HIP source level.
//  R6:    LDS-resident pipeline via __builtin_amdgcn_global_load_lds (m97
//         pattern). DMA writes LDS at data-return -> nothing for the compiler
//         to corrupt. 4 slots x {x,z} x 4KB = 32KB/wg; stage-ahead A=3 ->
//         6 load_lds in flight per wave. Waves read only their own staged
//         quarter -> zero barriers. Hand-counted vmcnt (over-wait-safe):
//         prologue 4, steady 6, tail 2. ds_read->compute ordering is
//         compiler-managed lgkmcnt (safe); slot WAR is 1 step stale (safe).

constexpr int BATCH = 128;
constexpr int FDIM  = 8192;
constexpr int STEP  = BATCH * FDIM;   // elements per time step = 1,048,576
constexpr int VEC   = 4;              // float4 per thread (load_lds width 16B)
constexpr int D     = 4;              // LDS slots (power of 2)
constexpr int A     = 3;              // stage-ahead distance (< D)

typedef float v4f __attribute__((ext_vector_type(4)));

// global -> LDS async copy, 16B per lane. gsrc is PER-LANE, ldst must be
// WAVE-UNIFORM (HW writes ldst + lane*16).
#define GLD16(gsrc, ldst)                                                  \
    __builtin_amdgcn_global_load_lds(                                      \
        (const __attribute__((address_space(1))) unsigned int*)(gsrc),     \
        (__attribute__((address_space(3))) unsigned int*)(ldst), 16, 0, 0)

__device__ __forceinline__ void lif_step(const v4f xt, const v4f zt,
                                         v4f& u, v4f& ss)
{
#pragma clang fp contract(off)
#pragma unroll
    for (int c = 0; c < VEC; ++c) {
        // u = beta*u + x   (separate mul + add, matches numpy)
        float uu = 0.5f * u[c];
        uu = uu + xt[c];
        // v = u - u_th
        float v = uu - 1.0f;
        // surr = (|z| / (2*delta)) * (|v| < delta*|z|)
        float az   = fabsf(zt[c]);
        float thr  = 0.05f * az;
        float ind  = (fabsf(v) < thr) ? 1.0f : 0.0f;
        float surr = (az / 0.1f) * ind;
        // h = (v > 0)
        float h = (v > 0.0f) ? 1.0f : 0.0f;
        // spike = (h - surr*v) + surr*v   (straight-through forward)
        float a     = surr * v;
        float spike = (h - a) + a;
        // u = u - spike * u_th
        u[c]  = uu - spike * 1.0f;
        ss[c] = spike;
    }
}

__global__ __launch_bounds__(256) void lif_zo_lds(
    const float* __restrict__ x,
    const float* __restrict__ z,
    float* __restrict__ out,
    int T)
{
#pragma clang fp contract(off)
    __shared__ v4f buf[D][2][256];          // 32 KB

    const int  ltid  = threadIdx.x;
    const int  gtid  = blockIdx.x * 256 + ltid;
    const long base  = (long)gtid * VEC;    // element index within a slab
    const int  wbase = ltid & ~63;          // wave-uniform LDS index base

    // Stage slab s into slot s%D. Per step this wave issues exactly
    // {1 store, 2 load_lds} VMEM ops — the vmcnt FIFO math relies on that.
    auto stage = [&](int s) {
        const int slot = s & (D - 1);
        GLD16(x + base + (long)s * STEP, &buf[slot][0][wbase]);
        GLD16(z + base + (long)s * STEP, &buf[slot][1][wbase]);
    };

    // Prologue: slabs 0..A-1 in flight (x then z per slab, in order).
#pragma unroll
    for (int j = 0; j < A; ++j) stage(j);

    v4f u = {0.0f, 0.0f, 0.0f, 0.0f};

    for (int t = 0; t < T; ++t) {
        const int slot = t & (D - 1);
        // Wait for slab t's pair to land in LDS. Counts are exact or
        // conservative (over-wait only):
        //   t=0: 4 ops after z0 (x1,z1,x2,z2). steady: 2 steps x 3 ops = 6.
        //   tail (no more loads): <=2 stores outstanding ahead of need.
        if (t < A) {
            asm volatile("s_waitcnt vmcnt(4)" ::: "memory");
        } else if (t < T - A + 1) {
            asm volatile("s_waitcnt vmcnt(6)" ::: "memory");
        } else {
            asm volatile("s_waitcnt vmcnt(2)" ::: "memory");
        }
        __builtin_amdgcn_sched_barrier(0);

        const v4f xt = buf[slot][0][ltid];   // ds_read_b128, compiler lgkmcnt
        const v4f zt = buf[slot][1][ltid];

        v4f ss;
        lif_step(xt, zt, u, ss);
        *reinterpret_cast<v4f*>(out + base + (long)t * STEP) = ss;

        // Refill the slot read at step t-1 (its ds_read drained via lgkmcnt
        // before that step's compute -> no WAR race with the DMA write).
        if (t + A < T) stage(t + A);
    }
}

// Generic fallback for unexpected T (correctness only; T=32 in this problem).
__global__ __launch_bounds__(256) void lif_zo_generic(
    const float* __restrict__ x,
    const float* __restrict__ z,
    float* __restrict__ out,
    int T)
{
#pragma clang fp contract(off)
    const int tid = blockIdx.x * blockDim.x + threadIdx.x;
    long idx = (long)tid * VEC;
    v4f u = {0.0f, 0.0f, 0.0f, 0.0f};
    for (int t = 0; t < T; ++t, idx += STEP) {
        const v4f xt = *reinterpret_cast<const v4f*>(x + idx);
        const v4f zt = *reinterpret_cast<const v4f*>(z + idx);
        v4f ss;
        lif_step(xt, zt, u, ss);
        *reinterpret_cast<v4f*>(out + idx) = ss;
    }
}

extern "C" void kernel_launch(void* const* d_in, const int* in_sizes, int n_in,
                              void* d_out, int out_size, void* d_ws, size_t ws_size,
                              hipStream_t stream)
{
    const float* x = (const float*)d_in[0];
    const float* z = (const float*)d_in[1];
    float* out = (float*)d_out;

    const int total = in_sizes[0];          // T * B * F
    const int T = total / STEP;             // = 32 for this problem

    const int nthreads = STEP / VEC;        // 262,144
    const int block = 256;
    const int grid = nthreads / block;      // 1024 -> 4 wg/CU (LDS 32KB)

    if (T >= 2 * A) {
        lif_zo_lds<<<grid, block, 0, stream>>>(x, z, out, T);
    } else {
        lif_zo_generic<<<grid, block, 0, stream>>>(x, z, out, T);
    }
}

// Round 7
// 308.293 us; speedup vs baseline: 1.0577x; 1.0069x over previous
//
#include <hip/hip_runtime.h>

// LeakyZOPlainOnce: 32-step LIF scan with LocalZO straight-through surrogate.
// inputs:  d_in[0] = x  (T*B*F fp32), d_in[1] = z (same shape)
// output:  d_out    = spikes (T*B*F fp32)
//
// Determinism: replicate numpy fp32 op order EXACTLY — separate mul+add (no
// FMA contraction), true IEEE division by 0.1f, strict comparisons.
//
// History:
//  R1/R2: occupancy 38%->71% alone did NOT raise BW.
//  R3:    rotation-copy pipeline -> per-step vmcnt drain, ~2.5 TB/s.
//  R4:    full unroll, compiler-scheduled: VGPR=40 proves loads sunk to
//         point-of-use (depth ~1). 122 us.
//  R5:    asm register pipeline: numerically wrong (compiler may copy an
//         in-flight "=v" dest before the hand waitcnt). Abandoned.
//  R6:    LDS-DMA pipeline, PROVABLE depth 3 (6-9 VMEM in flight/wave,
//         hand vmcnt): 113 us — identical to depth-1. Per-wave MLP is NOT
//         the constraint. Plateau ~3.56 TB/s aggregate = ~5.8 B/cyc/CU
//         service rate -> queueing-limited; only more independent
//         requesters (occupancy) x depth can beat it.
//  R7:    the untested corner: occupancy AND depth. VEC=2 -> 2048 wg ->
//         32 waves/CU ceiling; LB(256,8) caps VGPR at 64; full unroll with
//         PF=8 register pipeline, plain C++ loads (compiler-managed counted
//         waits), sched_barrier(0) fence per step so the scheduler cannot
//         sink prefetches (the R4 failure, now enforced). 256 KB/CU in
//         flight. If this stays ~113 us -> hardware service ceiling ->
//         ROOFLINE.

constexpr int BATCH = 128;
constexpr int FDIM  = 8192;
constexpr int STEP  = BATCH * FDIM;   // elements per time step = 1,048,576
constexpr int VEC   = 2;              // 2 floats per thread
constexpr int PF    = 8;              // pipeline depth (T >= PF required)

typedef float v2f __attribute__((ext_vector_type(2)));

__device__ __forceinline__ void lif2(const v2f xt, const v2f zt,
                                     v2f& u, v2f& ss)
{
#pragma clang fp contract(off)
#pragma unroll
    for (int c = 0; c < VEC; ++c) {
        // u = beta*u + x   (separate mul + add, matches numpy)
        float uu = 0.5f * u[c];
        uu = uu + xt[c];
        // v = u - u_th
        float v = uu - 1.0f;
        // surr = (|z| / (2*delta)) * (|v| < delta*|z|)
        float az   = fabsf(zt[c]);
        float thr  = 0.05f * az;
        float ind  = (fabsf(v) < thr) ? 1.0f : 0.0f;
        float surr = (az / 0.1f) * ind;
        // h = (v > 0)
        float h = (v > 0.0f) ? 1.0f : 0.0f;
        // spike = (h - surr*v) + surr*v   (straight-through forward)
        float a     = surr * v;
        float spike = (h - a) + a;
        // u = u - spike * u_th
        u[c]  = uu - spike * 1.0f;
        ss[c] = spike;
    }
}

// Compile-time recursion: buffer slot (t % PF) is constexpr -> buffers stay
// in registers (rule #20). sched_barrier(0) at each step boundary pins every
// prefetch PF steps ahead of its use; the compiler computes the counted
// vmcnt for the use itself (it does this correctly; only its SINKING freedom
// is removed).
template<int t, int T>
__device__ __forceinline__ void steps(const float* __restrict__ x,
                                      const float* __restrict__ z,
                                      float* __restrict__ out, long base,
                                      v2f (&xb)[PF], v2f (&zb)[PF], v2f& u)
{
    if constexpr (t < T) {
        constexpr int c = t % PF;
        v2f ss;
        lif2(xb[c], zb[c], u, ss);
        *reinterpret_cast<v2f*>(out + base + (long)t * STEP) = ss;
        if constexpr (t + PF < T) {
            xb[c] = *reinterpret_cast<const v2f*>(x + base + (long)(t + PF) * STEP);
            zb[c] = *reinterpret_cast<const v2f*>(z + base + (long)(t + PF) * STEP);
        }
        __builtin_amdgcn_sched_barrier(0);
        steps<t + 1, T>(x, z, out, base, xb, zb, u);
    }
}

template<int T>
__global__ __launch_bounds__(256, 8) void lif_zo_pipe(
    const float* __restrict__ x,
    const float* __restrict__ z,
    float* __restrict__ out)
{
#pragma clang fp contract(off)
    const int tid = blockIdx.x * blockDim.x + threadIdx.x;
    const long base = (long)tid * VEC;

    v2f xb[PF], zb[PF];
    // Prologue: slabs 0..PF-1 issued back-to-back (16 loads in flight).
#pragma unroll
    for (int j = 0; j < PF; ++j) {
        xb[j] = *reinterpret_cast<const v2f*>(x + base + (long)j * STEP);
        zb[j] = *reinterpret_cast<const v2f*>(z + base + (long)j * STEP);
    }
    __builtin_amdgcn_sched_barrier(0);

    v2f u = {0.0f, 0.0f};
    steps<0, T>(x, z, out, base, xb, zb, u);
}

// Generic fallback for unexpected T (correctness only; T=32 in this problem).
__global__ __launch_bounds__(256) void lif_zo_generic(
    const float* __restrict__ x,
    const float* __restrict__ z,
    float* __restrict__ out,
    int T)
{
#pragma clang fp contract(off)
    const int tid = blockIdx.x * blockDim.x + threadIdx.x;
    long idx = (long)tid * VEC;
    v2f u = {0.0f, 0.0f};
    for (int t = 0; t < T; ++t, idx += STEP) {
        const v2f xt = *reinterpret_cast<const v2f*>(x + idx);
        const v2f zt = *reinterpret_cast<const v2f*>(z + idx);
        v2f ss;
        lif2(xt, zt, u, ss);
        *reinterpret_cast<v2f*>(out + idx) = ss;
    }
}

extern "C" void kernel_launch(void* const* d_in, const int* in_sizes, int n_in,
                              void* d_out, int out_size, void* d_ws, size_t ws_size,
                              hipStream_t stream)
{
    const float* x = (const float*)d_in[0];
    const float* z = (const float*)d_in[1];
    float* out = (float*)d_out;

    const int total = in_sizes[0];          // T * B * F
    const int T = total / STEP;             // = 32 for this problem

    const int nthreads = STEP / VEC;        // 524,288
    const int block = 256;
    const int grid = nthreads / block;      // 2048 -> 8 wg/CU, 32 waves/CU

    if (T == 32) {
        lif_zo_pipe<32><<<grid, block, 0, stream>>>(x, z, out);
    } else {
        lif_zo_generic<<<grid, block, 0, stream>>>(x, z, out, T);
    }
}